// Round 14
// baseline (516.719 us; speedup 1.0000x reference)
//
#include <hip/hip_runtime.h>
#include <cstddef>

typedef __attribute__((ext_vector_type(8))) short short8;
typedef __attribute__((ext_vector_type(4))) float f32x4;
typedef __attribute__((ext_vector_type(8))) _Float16 half8;
typedef __attribute__((ext_vector_type(4))) _Float16 half4;
typedef __attribute__((ext_vector_type(4))) unsigned short ushortx4;

__device__ __forceinline__ unsigned short f2h(float f) {
    union { _Float16 h; unsigned short u; } x; x.h = (_Float16)f; return x.u;
}
__device__ __forceinline__ float lrelu(float v) { return v > 0.f ? v : 0.2f * v; }

// ---------------- prep: zero cnt | f32->f16 pad | weight transposes ----------------
// One launch, disjoint block ranges.

__global__ void prep_kernel(const float* __restrict__ x, unsigned short* __restrict__ xb,
                            int N, int Mp,
                            const float* __restrict__ W1, const float* __restrict__ W2,
                            const float* __restrict__ Wm, const float* __restrict__ Wl,
                            unsigned short* __restrict__ W1t, unsigned short* __restrict__ W2t,
                            unsigned short* __restrict__ WmlT,
                            int* __restrict__ cnt, int nZero, int nConv) {
    int b = blockIdx.x;
    int tid = threadIdx.x;
    if (b < nZero) {
        int i = b * 256 + tid;
        if (i < N) cnt[i] = 0;
    } else if (b < nZero + nConv) {
        int i = (b - nZero) * 256 + tid;           // float4 quad index
        int total = (Mp * 256) >> 2;
        if (i >= total) return;
        int r = (i * 4) >> 8;                      // cols = 256
        ushort4 o;
        if (r < N) {
            float4 v = *(const float4*)(x + (size_t)i * 4);
            o = make_ushort4(f2h(v.x), f2h(v.y), f2h(v.z), f2h(v.w));
        } else {
            o = make_ushort4(0, 0, 0, 0);
        }
        *(ushort4*)(xb + (size_t)i * 4) = o;
    } else {
        int i = (b - nZero - nConv) * 256 + tid;
        if (i < 65536) {
            int k = i >> 8, n = i & 255;
            W1t[(size_t)n * 256 + k] = f2h(W1[i]);
        } else if (i < 65536 + 131072) {
            int j = i - 65536;
            int k = j >> 9, n = j & 511;
            W2t[(size_t)n * 256 + k] = f2h(W2[j]);
        } else if (i < 65536 + 131072 + 65536) {
            int j = i - 196608;
            int k = j >> 7, n = j & 127;
            WmlT[(size_t)n * 512 + k] = f2h(Wm[j]);
        } else if (i < 65536 + 131072 + 131072) {
            int j = i - 262144;
            int k = j >> 7, n = j & 127;
            WmlT[(size_t)(128 + n) * 512 + k] = f2h(Wl[j]);
        }
    }
}

// ---------------- CSR: scan (also re-zeroes cnt as scatter cursor) ----------------

__global__ void scan_kernel(int* __restrict__ cnt, int* __restrict__ rp, int n) {
    __shared__ int sh[1024];
    int t = threadIdx.x;
    int chunk = (n + 1023) >> 10;
    int beg = t * chunk;
    int end = beg + chunk < n ? beg + chunk : n;
    int local = 0;
    for (int i = beg; i < end; i++) local += cnt[i];
    sh[t] = local;
    __syncthreads();
    for (int off = 1; off < 1024; off <<= 1) {
        int v = (t >= off) ? sh[t - off] : 0;
        __syncthreads();
        sh[t] += v;
        __syncthreads();
    }
    int run = (t == 0) ? 0 : sh[t - 1];
    for (int i = beg; i < end; i++) {
        int c = cnt[i];
        cnt[i] = 0;
        run += c;
        rp[i + 1] = run;
    }
    if (t == 0) rp[0] = 0;
}

__global__ void scatter_edges_kernel(const int* __restrict__ ei, int E, int N,
                                     const int* __restrict__ rp, int* __restrict__ cur,
                                     int* __restrict__ csrc) {
    int e = blockIdx.x * blockDim.x + threadIdx.x;
    if (e >= E + N) return;
    int s, d;
    if (e < E) { s = ei[e]; d = ei[E + e]; } else { s = e - E; d = s; }
    int pos = rp[d] + atomicAdd(&cur[d], 1);
    csrc[pos] = s;
}

// ---------------- f16 MFMA GEMM tile (device fn) + al epilogue ----------------
// 64x128 tile, BK=32, 256 threads (2x2 waves of 32x64), software-pipelined
// staging. Epilogue: per-wave 16-lane reduce -> LDS -> 64 row-threads sum ->
// direct stores of al_s/al_d (no atomics; col-blocks own complete heads).

struct GemmSmem {
    short As[64 * 32];
    short Bs[128 * 32];
    float salS[64][4];
    float salD[64][4];
};

__device__ __forceinline__ void gemm_f16_tile(
    const unsigned short* __restrict__ A, const unsigned short* __restrict__ Bt,
    unsigned short* __restrict__ C, int M, int K, int Nc,
    float* __restrict__ al_s, float* __restrict__ al_d,
    const float* __restrict__ aslo, const float* __restrict__ adlo,
    const float* __restrict__ ashi, const float* __restrict__ adhi,
    int csplit, int Chead, int H, GemmSmem& sm, int bm, int bn, int tid) {
    int wave = tid >> 6, lane = tid & 63;
    int wm = (wave >> 1) * 32, wn = (wave & 1) * 64;
    int lm = lane & 15, lq = lane >> 4;

    f32x4 acc[2][4] = {};

    int c0 = tid, c1 = tid + 256;
    const unsigned short* Ap0 = A + (size_t)(bm + (c0 >> 2)) * K + (c0 & 3) * 8;
    const unsigned short* Bp0 = Bt + (size_t)(bn + (c0 >> 2)) * K + (c0 & 3) * 8;
    const unsigned short* Bp1 = Bt + (size_t)(bn + (c1 >> 2)) * K + (c1 & 3) * 8;

    short8 a0 = *(const short8*)(Ap0);
    short8 b0 = *(const short8*)(Bp0);
    short8 b1 = *(const short8*)(Bp1);

    for (int kk = 0; kk < K; kk += 32) {
        __syncthreads();
        *(short8*)&sm.As[c0 * 8] = a0;
        *(short8*)&sm.Bs[c0 * 8] = b0;
        *(short8*)&sm.Bs[c1 * 8] = b1;
        if (kk + 32 < K) {     // prefetch next tile before the MFMA burst
            a0 = *(const short8*)(Ap0 + kk + 32);
            b0 = *(const short8*)(Bp0 + kk + 32);
            b1 = *(const short8*)(Bp1 + kk + 32);
        }
        __syncthreads();
        half8 af[2], bf[4];
#pragma unroll
        for (int t = 0; t < 2; t++)
            af[t] = *(const half8*)&sm.As[(wm + t * 16 + lm) * 32 + lq * 8];
#pragma unroll
        for (int t = 0; t < 4; t++)
            bf[t] = *(const half8*)&sm.Bs[(wn + t * 16 + lm) * 32 + lq * 8];
#pragma unroll
        for (int tm = 0; tm < 2; tm++)
#pragma unroll
            for (int tn = 0; tn < 4; tn++)
                acc[tm][tn] = __builtin_amdgcn_mfma_f32_16x16x32_f16(
                    af[tm], bf[tn], acc[tm][tn], 0, 0, 0);
    }

    // C store (f16)
#pragma unroll
    for (int tm = 0; tm < 2; tm++) {
#pragma unroll
        for (int r = 0; r < 4; r++) {
            int row = bm + wm + tm * 16 + lq * 4 + r;
            if (row < M) {
#pragma unroll
                for (int tn = 0; tn < 4; tn++) {
                    int col = bn + wn + tn * 16 + lm;
                    C[(size_t)row * Nc + col] = f2h(acc[tm][tn][r]);
                }
            }
        }
    }

    // attention-logit partial dots -> LDS -> direct stores
    float asv[4], adv[4];
#pragma unroll
    for (int tn = 0; tn < 4; tn++) {
        int col = bn + wn + tn * 16 + lm;
        bool hi = col >= csplit;
        int cc = hi ? col - csplit : col;
        asv[tn] = hi ? ashi[cc] : aslo[cc];
        adv[tn] = hi ? adhi[cc] : adlo[cc];
    }
    int gb = wn >> 5;  // 0 or 2
#pragma unroll
    for (int tm = 0; tm < 2; tm++) {
#pragma unroll
        for (int r = 0; r < 4; r++) {
#pragma unroll
            for (int p = 0; p < 2; p++) {
                float s1 = acc[tm][2 * p][r] * asv[2 * p]
                         + acc[tm][2 * p + 1][r] * asv[2 * p + 1];
                float s2 = acc[tm][2 * p][r] * adv[2 * p]
                         + acc[tm][2 * p + 1][r] * adv[2 * p + 1];
#pragma unroll
                for (int off = 8; off >= 1; off >>= 1) {
                    s1 += __shfl_xor(s1, off);
                    s2 += __shfl_xor(s2, off);
                }
                if (lm == 0) {
                    int rl = wm + tm * 16 + lq * 4 + r;
                    sm.salS[rl][gb + p] = s1;
                    sm.salD[rl][gb + p] = s2;
                }
            }
        }
    }
    __syncthreads();
    if (tid < 64) {
        int row = bm + tid;
        if (row < M) {
            int hb = bn / Chead;
            int HB = 128 / Chead;
            int GH = Chead >> 5;
            for (int i = 0; i < HB; i++) {
                float ss = 0.f, sd = 0.f;
                for (int j = 0; j < GH; j++) {
                    ss += sm.salS[tid][i * GH + j];
                    sd += sm.salD[tid][i * GH + j];
                }
                al_s[(size_t)row * H + hb + i] = ss;
                al_d[(size_t)row * H + hb + i] = sd;
            }
        }
    }
}

// plain GEMM launch (flattened tiles; nbx col-tiles)
__global__ __launch_bounds__(256) void gemm_f16_kernel(
    const unsigned short* __restrict__ A, const unsigned short* __restrict__ Bt,
    unsigned short* __restrict__ C, int M, int K, int Nc,
    float* __restrict__ al_s, float* __restrict__ al_d,
    const float* __restrict__ aslo, const float* __restrict__ adlo,
    const float* __restrict__ ashi, const float* __restrict__ adhi,
    int csplit, int Chead, int H, int nbx) {
    __shared__ GemmSmem sm;
    int b = blockIdx.x;
    int bn = (b % nbx) * 128;
    int bm = (b / nbx) * 64;
    gemm_f16_tile(A, Bt, C, M, K, Nc, al_s, al_d, aslo, adlo, ashi, adhi,
                  csplit, Chead, H, sm, bm, bn, threadIdx.x);
}

// GEMM-1 + edge-count fused in one launch (disjoint block ranges)
__global__ __launch_bounds__(256) void gemm1_count_kernel(
    const unsigned short* __restrict__ A, const unsigned short* __restrict__ Bt,
    unsigned short* __restrict__ C, int M, int K, int Nc,
    float* __restrict__ al_s, float* __restrict__ al_d,
    const float* __restrict__ aslo, const float* __restrict__ adlo,
    const float* __restrict__ ashi, const float* __restrict__ adhi,
    int csplit, int Chead, int H, int nbx, int nGemm,
    const int* __restrict__ ei, int E, int N, int* __restrict__ cnt) {
    __shared__ GemmSmem sm;
    int b = blockIdx.x;
    if (b < nGemm) {
        int bn = (b % nbx) * 128;
        int bm = (b / nbx) * 64;
        gemm_f16_tile(A, Bt, C, M, K, Nc, al_s, al_d, aslo, adlo, ashi, adhi,
                      csplit, Chead, H, sm, bm, bn, threadIdx.x);
    } else {
        int e = (b - nGemm) * 256 + threadIdx.x;
        if (e < E + N) {
            int d = (e < E) ? ei[E + e] : (e - E);
            atomicAdd(&cnt[d], 1);
        }
    }
}

// ---------------- fused per-node softmax + aggregate, 4 nodes/block ----------------
// 4 waves/block, each wave owns one dst node. Lane-per-edge softmax via
// butterfly shuffles; alpha parked in LDS; gather-aggregate with packed f16
// FMAs (V channels/lane), 8-edge unroll. Outputs stored non-temporally (they
// are streamed by the next GEMM; keeps L2 free for the gather table).
// MODE 0: concat + bias + ReLU, f16 out. MODE 1: 8 heads x 32ch -> head-mean
// over groups 0-3 / 4-7 + bias, f32 out1/out2.

template <int H4, int V, int MODE>
__global__ __launch_bounds__(256) void gat_fused_kernel(
    const int* __restrict__ rp, const int* __restrict__ csrc,
    const float* __restrict__ al_s, const float* __restrict__ al_d,
    const unsigned short* __restrict__ h,
    const float* __restrict__ bias1, const float* __restrict__ bias2,
    void* __restrict__ out1v, void* __restrict__ out2v, int HC, int C, int N) {
    const int H = 4 * H4;
    __shared__ int lds_src[4][64];
    __shared__ float lds_alpha[4][64 * 4 * H4];
    __shared__ float shred[4][256];
    int wv = threadIdx.x >> 6;
    int lane = threadIdx.x & 63;
    int n = blockIdx.x * 4 + wv;
    if (n >= N) return;
    int beg = rp[n], end = rp[n + 1];
    int deg = end - beg;

    float ad[H];
#pragma unroll
    for (int g = 0; g < H4; g++)
        *(float4*)&ad[g * 4] = *(const float4*)(al_d + (size_t)n * H + g * 4);

    int ch = lane * V;
    int hh = ch / C;
    half8 acc8 = {};
    half4 acc4 = {};

    if (deg <= 64) {
        bool act = lane < deg;
        int s = act ? csrc[beg + lane] : 0;
        float v[H], m[H], ex[H], sum[H];
#pragma unroll
        for (int g = 0; g < H4; g++) {
            float4 as = *(const float4*)(al_s + (size_t)s * H + g * 4);
            v[g * 4 + 0] = lrelu(as.x + ad[g * 4 + 0]);
            v[g * 4 + 1] = lrelu(as.y + ad[g * 4 + 1]);
            v[g * 4 + 2] = lrelu(as.z + ad[g * 4 + 2]);
            v[g * 4 + 3] = lrelu(as.w + ad[g * 4 + 3]);
        }
#pragma unroll
        for (int j = 0; j < H; j++) m[j] = act ? v[j] : -3.402823466e38f;
#pragma unroll
        for (int off = 32; off >= 1; off >>= 1)
#pragma unroll
            for (int j = 0; j < H; j++) m[j] = fmaxf(m[j], __shfl_xor(m[j], off));
#pragma unroll
        for (int j = 0; j < H; j++) {
            ex[j] = act ? __expf(v[j] - m[j]) : 0.f;
            sum[j] = ex[j];
        }
#pragma unroll
        for (int off = 32; off >= 1; off >>= 1)
#pragma unroll
            for (int j = 0; j < H; j++) sum[j] += __shfl_xor(sum[j], off);
        if (act) {
            lds_src[wv][lane] = s;
#pragma unroll
            for (int g = 0; g < H4; g++) {
                float4 o;
                o.x = ex[g * 4 + 0] / (sum[g * 4 + 0] + 1e-16f);
                o.y = ex[g * 4 + 1] / (sum[g * 4 + 1] + 1e-16f);
                o.z = ex[g * 4 + 2] / (sum[g * 4 + 2] + 1e-16f);
                o.w = ex[g * 4 + 3] / (sum[g * 4 + 3] + 1e-16f);
                *(float4*)&lds_alpha[wv][lane * H + g * 4] = o;
            }
        }
        int t = 0;
        for (; t + 8 <= deg; t += 8) {
            int ss[8]; float av[8];
#pragma unroll
            for (int u = 0; u < 8; u++) {
                ss[u] = lds_src[wv][t + u];
                av[u] = lds_alpha[wv][(t + u) * H + hh];
            }
            if constexpr (V == 8) {
                half8 hv[8];
#pragma unroll
                for (int u = 0; u < 8; u++)
                    hv[u] = *(const half8*)(h + (size_t)ss[u] * HC + ch);
#pragma unroll
                for (int u = 0; u < 8; u++) {
                    _Float16 ah = (_Float16)av[u];
                    half8 a2;
#pragma unroll
                    for (int i = 0; i < 8; i++) a2[i] = ah;
                    acc8 += hv[u] * a2;
                }
            } else {
                half4 hv[8];
#pragma unroll
                for (int u = 0; u < 8; u++)
                    hv[u] = *(const half4*)(h + (size_t)ss[u] * HC + ch);
#pragma unroll
                for (int u = 0; u < 8; u++) {
                    _Float16 ah = (_Float16)av[u];
                    half4 a2;
#pragma unroll
                    for (int i = 0; i < 4; i++) a2[i] = ah;
                    acc4 += hv[u] * a2;
                }
            }
        }
        for (; t < deg; t++) {
            int s2 = lds_src[wv][t];
            _Float16 ah = (_Float16)lds_alpha[wv][t * H + hh];
            if constexpr (V == 8) {
                half8 hv = *(const half8*)(h + (size_t)s2 * HC + ch);
                half8 a2;
#pragma unroll
                for (int i = 0; i < 8; i++) a2[i] = ah;
                acc8 += hv * a2;
            } else {
                half4 hv = *(const half4*)(h + (size_t)s2 * HC + ch);
                half4 a2;
#pragma unroll
                for (int i = 0; i < 4; i++) a2[i] = ah;
                acc4 += hv * a2;
            }
        }
    } else {
        float m[H], sum[H];
#pragma unroll
        for (int j = 0; j < H; j++) m[j] = -3.402823466e38f;
        for (int e = beg + lane; e < end; e += 64) {
            int s = csrc[e];
#pragma unroll
            for (int g = 0; g < H4; g++) {
                float4 as = *(const float4*)(al_s + (size_t)s * H + g * 4);
                m[g * 4 + 0] = fmaxf(m[g * 4 + 0], lrelu(as.x + ad[g * 4 + 0]));
                m[g * 4 + 1] = fmaxf(m[g * 4 + 1], lrelu(as.y + ad[g * 4 + 1]));
                m[g * 4 + 2] = fmaxf(m[g * 4 + 2], lrelu(as.z + ad[g * 4 + 2]));
                m[g * 4 + 3] = fmaxf(m[g * 4 + 3], lrelu(as.w + ad[g * 4 + 3]));
            }
        }
#pragma unroll
        for (int off = 32; off >= 1; off >>= 1)
#pragma unroll
            for (int j = 0; j < H; j++) m[j] = fmaxf(m[j], __shfl_xor(m[j], off));
#pragma unroll
        for (int j = 0; j < H; j++) sum[j] = 0.f;
        for (int e = beg + lane; e < end; e += 64) {
            int s = csrc[e];
#pragma unroll
            for (int g = 0; g < H4; g++) {
                float4 as = *(const float4*)(al_s + (size_t)s * H + g * 4);
                sum[g * 4 + 0] += __expf(lrelu(as.x + ad[g * 4 + 0]) - m[g * 4 + 0]);
                sum[g * 4 + 1] += __expf(lrelu(as.y + ad[g * 4 + 1]) - m[g * 4 + 1]);
                sum[g * 4 + 2] += __expf(lrelu(as.z + ad[g * 4 + 2]) - m[g * 4 + 2]);
                sum[g * 4 + 3] += __expf(lrelu(as.w + ad[g * 4 + 3]) - m[g * 4 + 3]);
            }
        }
#pragma unroll
        for (int off = 32; off >= 1; off >>= 1)
#pragma unroll
            for (int j = 0; j < H; j++) sum[j] += __shfl_xor(sum[j], off);
        float r[H];
#pragma unroll
        for (int j = 0; j < H; j++) r[j] = 1.0f / (sum[j] + 1e-16f);
        for (int base = beg; base < end; base += 64) {
            int cn = end - base < 64 ? end - base : 64;
            if (lane < cn) {
                int s = csrc[base + lane];
                lds_src[wv][lane] = s;
#pragma unroll
                for (int g = 0; g < H4; g++) {
                    float4 as = *(const float4*)(al_s + (size_t)s * H + g * 4);
                    float4 o;
                    o.x = __expf(lrelu(as.x + ad[g * 4 + 0]) - m[g * 4 + 0]) * r[g * 4 + 0];
                    o.y = __expf(lrelu(as.y + ad[g * 4 + 1]) - m[g * 4 + 1]) * r[g * 4 + 1];
                    o.z = __expf(lrelu(as.z + ad[g * 4 + 2]) - m[g * 4 + 2]) * r[g * 4 + 2];
                    o.w = __expf(lrelu(as.w + ad[g * 4 + 3]) - m[g * 4 + 3]) * r[g * 4 + 3];
                    *(float4*)&lds_alpha[wv][lane * H + g * 4] = o;
                }
            }
            for (int t = 0; t < cn; t++) {
                int s2 = lds_src[wv][t];
                _Float16 ah = (_Float16)lds_alpha[wv][t * H + hh];
                if constexpr (V == 8) {
                    half8 hv = *(const half8*)(h + (size_t)s2 * HC + ch);
                    half8 a2;
#pragma unroll
                    for (int i = 0; i < 8; i++) a2[i] = ah;
                    acc8 += hv * a2;
                } else {
                    half4 hv = *(const half4*)(h + (size_t)s2 * HC + ch);
                    half4 a2;
#pragma unroll
                    for (int i = 0; i < 4; i++) a2[i] = ah;
                    acc4 += hv * a2;
                }
            }
        }
    }

    float accf[V];
#pragma unroll
    for (int j = 0; j < V; j++)
        accf[j] = (V == 8) ? (float)acc8[j] : (float)acc4[j];

    if constexpr (MODE == 0) {
        unsigned short* out = (unsigned short*)out1v;
        unsigned short o[V];
#pragma unroll
        for (int j = 0; j < V; j++)
            o[j] = f2h(fmaxf(accf[j] + bias1[ch + j], 0.f));
        if constexpr (V == 8) {
            short8 ov;
#pragma unroll
            for (int j = 0; j < 8; j++) ov[j] = (short)o[j];
            __builtin_nontemporal_store(ov, (short8*)(out + (size_t)n * HC + ch));
        } else {
            ushortx4 ov;
#pragma unroll
            for (int j = 0; j < 4; j++) ov[j] = o[j];
            __builtin_nontemporal_store(ov, (ushortx4*)(out + (size_t)n * HC + ch));
        }
    } else {
        *(float4*)&shred[wv][ch] = make_float4(accf[0], accf[1], accf[2], accf[3]);
        if (lane < 32) {
            float v1 = (shred[wv][lane] + shred[wv][lane + 32] + shred[wv][lane + 64]
                        + shred[wv][lane + 96]) * 0.25f + bias1[lane];
            float v2 = (shred[wv][lane + 128] + shred[wv][lane + 160]
                        + shred[wv][lane + 192] + shred[wv][lane + 224]) * 0.25f
                       + bias2[lane];
            __builtin_nontemporal_store(v1, (float*)out1v + (size_t)n * 32 + lane);
            __builtin_nontemporal_store(v2, (float*)out2v + (size_t)n * 32 + lane);
        }
    }
}

// ---------------- orchestration ----------------

extern "C" void kernel_launch(void* const* d_in, const int* in_sizes, int n_in,
                              void* d_out, int out_size, void* d_ws, size_t ws_size,
                              hipStream_t stream) {
    (void)n_in; (void)out_size; (void)ws_size;
    const float* x   = (const float*)d_in[0];
    const int*   ei  = (const int*)d_in[1];
    const float* W1  = (const float*)d_in[2];
    const float* as1 = (const float*)d_in[3];
    const float* ad1 = (const float*)d_in[4];
    const float* b1  = (const float*)d_in[5];
    const float* W2  = (const float*)d_in[6];
    const float* as2 = (const float*)d_in[7];
    const float* ad2 = (const float*)d_in[8];
    const float* b2  = (const float*)d_in[9];
    const float* Wm  = (const float*)d_in[10];
    const float* a_sm = (const float*)d_in[11];
    const float* a_dm = (const float*)d_in[12];
    const float* bm  = (const float*)d_in[13];
    const float* Wl  = (const float*)d_in[14];
    const float* a_sl = (const float*)d_in[15];
    const float* a_dl = (const float*)d_in[16];
    const float* bl  = (const float*)d_in[17];
    float* outp = (float*)d_out;

    const int N  = in_sizes[0] / 256;   // 30000
    const int E  = in_sizes[1] / 2;     // 480000
    const int ET = E + N;               // with self loops
    const int gM128 = (N + 127) / 128;  // 235
    const int Mp = gM128 * 128;         // 30080 (padded rows; >= 470*64)
    const int gM64 = (N + 63) / 64;     // 469

    auto align_up = [](size_t v) { return (v + 255) & ~(size_t)255; };
    char* w = (char*)d_ws;
    int* row_ptr = (int*)w;  w += align_up((size_t)(N + 1) * 4);
    int* cnt     = (int*)w;  w += align_up((size_t)N * 4);
    int* csrc    = (int*)w;  w += align_up((size_t)ET * 4);
    float* al_s  = (float*)w; w += align_up((size_t)N * 8 * 4);
    float* al_d  = (float*)w; w += align_up((size_t)N * 8 * 4);
    unsigned short* xb   = (unsigned short*)w; w += align_up((size_t)Mp * 256 * 2);
    unsigned short* W1t  = (unsigned short*)w; w += align_up((size_t)256 * 256 * 2);
    unsigned short* W2t  = (unsigned short*)w; w += align_up((size_t)512 * 256 * 2);
    unsigned short* WmlT = (unsigned short*)w; w += align_up((size_t)256 * 512 * 2);
    unsigned short* bufH = (unsigned short*)w; w += align_up((size_t)Mp * 512 * 2);
    unsigned short* bufO = (unsigned short*)w; w += align_up((size_t)Mp * 512 * 2);

    // ---- prep: zero cnt | x f32->f16 | weight transposes (one launch) ----
    int nZero = (N + 255) / 256;                 // 118
    int nConv = (Mp * 256 / 4 + 255) / 256;      // 7520
    int nTrans = (393216 + 255) / 256;           // 1536
    prep_kernel<<<nZero + nConv + nTrans, 256, 0, stream>>>(
        x, xb, N, Mp, W1, W2, Wm, Wl, W1t, W2t, WmlT, cnt, nZero, nConv);

    int gzE = (ET + 255) / 256;                  // 1993
    int gF = (N + 3) / 4;

    // ---- GEMM-1 (L1: 256 -> 256, al epilogue) + edge count, one launch ----
    int nGemm1 = 2 * gM64;                       // 938
    gemm1_count_kernel<<<nGemm1 + gzE, 256, 0, stream>>>(
        xb, W1t, bufH, N, 256, 256, al_s, al_d, as1, ad1, as1, ad1, 256, 64, 4,
        2, nGemm1, ei, E, N, cnt);

    // ---- CSR: scan (re-zeroes cnt), scatter ----
    scan_kernel<<<1, 1024, 0, stream>>>(cnt, row_ptr, N);
    scatter_edges_kernel<<<gzE, 256, 0, stream>>>(ei, E, N, row_ptr, cnt, csrc);

    // ---- Layer 1 fused: softmax + aggregate + ReLU ----
    gat_fused_kernel<1, 4, 0><<<gF, 256, 0, stream>>>(
        row_ptr, csrc, al_s, al_d, bufH, b1, nullptr, bufO, nullptr, 256, 64, N);

    // ---- Layer 2: GAT(256 -> 4x128, concat) + ReLU ----
    gemm_f16_kernel<<<4 * gM64, 256, 0, stream>>>(
        bufO, W2t, bufH, N, 256, 512, al_s, al_d, as2, ad2, as2, ad2, 512, 128, 4, 4);
    gat_fused_kernel<1, 8, 0><<<gF, 256, 0, stream>>>(
        row_ptr, csrc, al_s, al_d, bufH, b2, nullptr, bufO, nullptr, 512, 128, N);

    // ---- Layers 3+4 batched: GAT(512 -> 8x32, mean per 4-head group) ----
    gemm_f16_kernel<<<2 * gM64, 256, 0, stream>>>(
        bufO, WmlT, bufH, N, 512, 256, al_s, al_d, a_sm, a_dm, a_sl, a_dl, 128, 32, 8, 2);
    gat_fused_kernel<2, 4, 1><<<gF, 256, 0, stream>>>(
        row_ptr, csrc, al_s, al_d, bufH, bm, bl, outp, outp + (size_t)N * 32, 256, 32, N);
}

// Round 15
// 446.840 us; speedup vs baseline: 1.1564x; 1.1564x over previous
//
#include <hip/hip_runtime.h>
#include <cstddef>

typedef __attribute__((ext_vector_type(8))) short short8;
typedef __attribute__((ext_vector_type(4))) float f32x4;
typedef __attribute__((ext_vector_type(8))) _Float16 half8;
typedef __attribute__((ext_vector_type(4))) _Float16 half4;

__device__ __forceinline__ unsigned short f2h(float f) {
    union { _Float16 h; unsigned short u; } x; x.h = (_Float16)f; return x.u;
}
__device__ __forceinline__ float lrelu(float v) { return v > 0.f ? v : 0.2f * v; }

// ---------------- CSR build ----------------

__global__ void count_edges_kernel(const int* __restrict__ ei, int E, int N,
                                   int* __restrict__ cnt) {
    int e = blockIdx.x * blockDim.x + threadIdx.x;
    if (e >= E + N) return;
    int d = (e < E) ? ei[E + e] : (e - E);  // self loops appended
    atomicAdd(&cnt[d], 1);
}

// single block, 1024 threads; also re-zeroes cnt for the scatter cursor.
__global__ void scan_kernel(int* __restrict__ cnt, int* __restrict__ rp, int n) {
    __shared__ int sh[1024];
    int t = threadIdx.x;
    int chunk = (n + 1023) >> 10;
    int beg = t * chunk;
    int end = beg + chunk < n ? beg + chunk : n;
    int local = 0;
    for (int i = beg; i < end; i++) local += cnt[i];
    sh[t] = local;
    __syncthreads();
    for (int off = 1; off < 1024; off <<= 1) {
        int v = (t >= off) ? sh[t - off] : 0;
        __syncthreads();
        sh[t] += v;
        __syncthreads();
    }
    int run = (t == 0) ? 0 : sh[t - 1];
    for (int i = beg; i < end; i++) {
        int c = cnt[i];
        cnt[i] = 0;
        run += c;
        rp[i + 1] = run;
    }
    if (t == 0) rp[0] = 0;
}

__global__ void scatter_edges_kernel(const int* __restrict__ ei, int E, int N,
                                     const int* __restrict__ rp, int* __restrict__ cur,
                                     int* __restrict__ csrc) {
    int e = blockIdx.x * blockDim.x + threadIdx.x;
    if (e >= E + N) return;
    int s, d;
    if (e < E) { s = ei[e]; d = ei[E + e]; } else { s = e - E; d = s; }
    int pos = rp[d] + atomicAdd(&cur[d], 1);
    csrc[pos] = s;
}

// ---------------- dtype prep ----------------

__global__ void f32_to_f16_pad4_kernel(const float* __restrict__ in,
                                       unsigned short* __restrict__ out,
                                       int rows, int cols, int padRows) {
    int i = blockIdx.x * blockDim.x + threadIdx.x;
    int total = (padRows * cols) >> 2;
    if (i >= total) return;
    int r = (i * 4) / cols;
    ushort4 o;
    if (r < rows) {
        float4 v = *(const float4*)(in + (size_t)i * 4);
        o = make_ushort4(f2h(v.x), f2h(v.y), f2h(v.z), f2h(v.w));
    } else {
        o = make_ushort4(0, 0, 0, 0);
    }
    *(ushort4*)(out + (size_t)i * 4) = o;
}

// All four weight transposes in one launch (f32 -> f16, [K,Nc] -> [Nc,K]).
__global__ void transpose_all_kernel(
    const float* __restrict__ W1, const float* __restrict__ W2,
    const float* __restrict__ Wm, const float* __restrict__ Wl,
    unsigned short* __restrict__ W1t, unsigned short* __restrict__ W2t,
    unsigned short* __restrict__ WmlT) {
    int i = blockIdx.x * blockDim.x + threadIdx.x;
    if (i < 65536) {
        int k = i >> 8, n = i & 255;
        W1t[(size_t)n * 256 + k] = f2h(W1[i]);
    } else if (i < 65536 + 131072) {
        int j = i - 65536;
        int k = j >> 9, n = j & 511;
        W2t[(size_t)n * 256 + k] = f2h(W2[j]);
    } else if (i < 65536 + 131072 + 65536) {
        int j = i - 196608;
        int k = j >> 7, n = j & 127;
        WmlT[(size_t)n * 512 + k] = f2h(Wm[j]);
    } else if (i < 65536 + 131072 + 131072) {
        int j = i - 262144;
        int k = j >> 7, n = j & 127;
        WmlT[(size_t)(128 + n) * 512 + k] = f2h(Wl[j]);
    }
}

// ---------------- f16 MFMA GEMM (software-pipelined) + al epilogue ----------------
// C[M,Nc] = A[Mp,K] @ Bt[Nc,K]^T; 64x128 tile, BK=32, 256 threads (2x2 waves of
// 32x64). K-loop software pipeline: next tile's global loads are issued right
// after this tile's LDS writes, BEFORE the MFMA burst.
// Epilogue: cols [bn,bn+128) contain complete heads; per-wave 16-lane reduce ->
// LDS -> 64 row-threads sum -> direct stores of al_s/al_d (no atomics).

__global__ __launch_bounds__(256) void gemm_f16_kernel(
    const unsigned short* __restrict__ A, const unsigned short* __restrict__ Bt,
    unsigned short* __restrict__ C, int M, int K, int Nc,
    float* __restrict__ al_s, float* __restrict__ al_d,
    const float* __restrict__ aslo, const float* __restrict__ adlo,
    const float* __restrict__ ashi, const float* __restrict__ adhi,
    int csplit, int Chead, int H) {
    __shared__ short As[64 * 32];
    __shared__ short Bs[128 * 32];
    __shared__ float salS[64][4];
    __shared__ float salD[64][4];
    int tid = threadIdx.x;
    int bm = blockIdx.y * 64;
    int bn = blockIdx.x * 128;
    int wave = tid >> 6, lane = tid & 63;
    int wm = (wave >> 1) * 32, wn = (wave & 1) * 64;
    int lm = lane & 15, lq = lane >> 4;

    f32x4 acc[2][4] = {};

    int c0 = tid, c1 = tid + 256;
    const unsigned short* Ap0 = A + (size_t)(bm + (c0 >> 2)) * K + (c0 & 3) * 8;
    const unsigned short* Bp0 = Bt + (size_t)(bn + (c0 >> 2)) * K + (c0 & 3) * 8;
    const unsigned short* Bp1 = Bt + (size_t)(bn + (c1 >> 2)) * K + (c1 & 3) * 8;

    short8 a0 = *(const short8*)(Ap0);
    short8 b0 = *(const short8*)(Bp0);
    short8 b1 = *(const short8*)(Bp1);

    for (int kk = 0; kk < K; kk += 32) {
        __syncthreads();           // prev iter's LDS frag reads done
        *(short8*)&As[c0 * 8] = a0;
        *(short8*)&Bs[c0 * 8] = b0;
        *(short8*)&Bs[c1 * 8] = b1;
        if (kk + 32 < K) {         // prefetch next tile BEFORE the MFMA burst
            a0 = *(const short8*)(Ap0 + kk + 32);
            b0 = *(const short8*)(Bp0 + kk + 32);
            b1 = *(const short8*)(Bp1 + kk + 32);
        }
        __syncthreads();           // this tile resident
        half8 af[2], bf[4];
#pragma unroll
        for (int t = 0; t < 2; t++)
            af[t] = *(const half8*)&As[(wm + t * 16 + lm) * 32 + lq * 8];
#pragma unroll
        for (int t = 0; t < 4; t++)
            bf[t] = *(const half8*)&Bs[(wn + t * 16 + lm) * 32 + lq * 8];
#pragma unroll
        for (int tm = 0; tm < 2; tm++)
#pragma unroll
            for (int tn = 0; tn < 4; tn++)
                acc[tm][tn] = __builtin_amdgcn_mfma_f32_16x16x32_f16(
                    af[tm], bf[tn], acc[tm][tn], 0, 0, 0);
    }

    // C store (f16)
#pragma unroll
    for (int tm = 0; tm < 2; tm++) {
#pragma unroll
        for (int r = 0; r < 4; r++) {
            int row = bm + wm + tm * 16 + lq * 4 + r;
            if (row < M) {
#pragma unroll
                for (int tn = 0; tn < 4; tn++) {
                    int col = bn + wn + tn * 16 + lm;
                    C[(size_t)row * Nc + col] = f2h(acc[tm][tn][r]);
                }
            }
        }
    }

    // attention-logit partial dots -> LDS (each (row, 32-col group) owned by
    // exactly one wave; no races)
    float asv[4], adv[4];
#pragma unroll
    for (int tn = 0; tn < 4; tn++) {
        int col = bn + wn + tn * 16 + lm;
        bool hi = col >= csplit;
        int cc = hi ? col - csplit : col;
        asv[tn] = hi ? ashi[cc] : aslo[cc];
        adv[tn] = hi ? adhi[cc] : adlo[cc];
    }
    int gb = wn >> 5;  // 0 or 2
#pragma unroll
    for (int tm = 0; tm < 2; tm++) {
#pragma unroll
        for (int r = 0; r < 4; r++) {
#pragma unroll
            for (int p = 0; p < 2; p++) {
                float s1 = acc[tm][2 * p][r] * asv[2 * p]
                         + acc[tm][2 * p + 1][r] * asv[2 * p + 1];
                float s2 = acc[tm][2 * p][r] * adv[2 * p]
                         + acc[tm][2 * p + 1][r] * adv[2 * p + 1];
#pragma unroll
                for (int off = 8; off >= 1; off >>= 1) {
                    s1 += __shfl_xor(s1, off);
                    s2 += __shfl_xor(s2, off);
                }
                if (lm == 0) {
                    int rl = wm + tm * 16 + lq * 4 + r;
                    salS[rl][gb + p] = s1;
                    salD[rl][gb + p] = s2;
                }
            }
        }
    }
    __syncthreads();
    if (tid < 64) {
        int row = bm + tid;
        if (row < M) {
            int hb = bn / Chead;       // first head in this col-block
            int HB = 128 / Chead;      // heads per col-block (1, 2, or 4)
            int GH = Chead >> 5;       // 32-col groups per head
            for (int i = 0; i < HB; i++) {
                float ss = 0.f, sd = 0.f;
                for (int j = 0; j < GH; j++) {
                    ss += salS[tid][i * GH + j];
                    sd += salD[tid][i * GH + j];
                }
                al_s[(size_t)row * H + hb + i] = ss;
                al_d[(size_t)row * H + hb + i] = sd;
            }
        }
    }
}

// ---------------- fused per-node softmax + aggregate, 4 nodes/block ----------------
// 4 waves/block, each wave owns one dst node. Lane-per-edge softmax via
// butterfly shuffles; alpha parked in LDS; gather-aggregate with PACKED F16
// FMAs (V channels/lane), 8-edge unroll.
// MODE 0: concat + bias + ReLU, f16 out. MODE 1: 8 heads x 32ch -> head-mean
// over groups 0-3 / 4-7 + bias, f32 out1/out2.

template <int H4, int V, int MODE>
__global__ __launch_bounds__(256) void gat_fused_kernel(
    const int* __restrict__ rp, const int* __restrict__ csrc,
    const float* __restrict__ al_s, const float* __restrict__ al_d,
    const unsigned short* __restrict__ h,
    const float* __restrict__ bias1, const float* __restrict__ bias2,
    void* __restrict__ out1v, void* __restrict__ out2v, int HC, int C, int N) {
    const int H = 4 * H4;
    __shared__ int lds_src[4][64];
    __shared__ float lds_alpha[4][64 * 4 * H4];
    __shared__ float shred[4][256];
    int wv = threadIdx.x >> 6;
    int lane = threadIdx.x & 63;
    int n = blockIdx.x * 4 + wv;
    if (n >= N) return;
    int beg = rp[n], end = rp[n + 1];
    int deg = end - beg;

    float ad[H];
#pragma unroll
    for (int g = 0; g < H4; g++)
        *(float4*)&ad[g * 4] = *(const float4*)(al_d + (size_t)n * H + g * 4);

    int ch = lane * V;
    int hh = ch / C;
    half8 acc8 = {};
    half4 acc4 = {};

    if (deg <= 64) {
        bool act = lane < deg;
        int s = act ? csrc[beg + lane] : 0;
        float v[H], m[H], ex[H], sum[H];
#pragma unroll
        for (int g = 0; g < H4; g++) {
            float4 as = *(const float4*)(al_s + (size_t)s * H + g * 4);
            v[g * 4 + 0] = lrelu(as.x + ad[g * 4 + 0]);
            v[g * 4 + 1] = lrelu(as.y + ad[g * 4 + 1]);
            v[g * 4 + 2] = lrelu(as.z + ad[g * 4 + 2]);
            v[g * 4 + 3] = lrelu(as.w + ad[g * 4 + 3]);
        }
#pragma unroll
        for (int j = 0; j < H; j++) m[j] = act ? v[j] : -3.402823466e38f;
#pragma unroll
        for (int off = 32; off >= 1; off >>= 1)
#pragma unroll
            for (int j = 0; j < H; j++) m[j] = fmaxf(m[j], __shfl_xor(m[j], off));
#pragma unroll
        for (int j = 0; j < H; j++) {
            ex[j] = act ? __expf(v[j] - m[j]) : 0.f;
            sum[j] = ex[j];
        }
#pragma unroll
        for (int off = 32; off >= 1; off >>= 1)
#pragma unroll
            for (int j = 0; j < H; j++) sum[j] += __shfl_xor(sum[j], off);
        if (act) {
            lds_src[wv][lane] = s;
#pragma unroll
            for (int g = 0; g < H4; g++) {
                float4 o;
                o.x = ex[g * 4 + 0] / (sum[g * 4 + 0] + 1e-16f);
                o.y = ex[g * 4 + 1] / (sum[g * 4 + 1] + 1e-16f);
                o.z = ex[g * 4 + 2] / (sum[g * 4 + 2] + 1e-16f);
                o.w = ex[g * 4 + 3] / (sum[g * 4 + 3] + 1e-16f);
                *(float4*)&lds_alpha[wv][lane * H + g * 4] = o;
            }
        }
        // wave-local LDS write->read (lockstep wave, compiler lgkmcnt ordering)
        int t = 0;
        for (; t + 8 <= deg; t += 8) {
            int ss[8]; float av[8];
#pragma unroll
            for (int u = 0; u < 8; u++) {
                ss[u] = lds_src[wv][t + u];
                av[u] = lds_alpha[wv][(t + u) * H + hh];
            }
            if constexpr (V == 8) {
                half8 hv[8];
#pragma unroll
                for (int u = 0; u < 8; u++)
                    hv[u] = *(const half8*)(h + (size_t)ss[u] * HC + ch);
#pragma unroll
                for (int u = 0; u < 8; u++) {
                    _Float16 ah = (_Float16)av[u];
                    half8 a2;
#pragma unroll
                    for (int i = 0; i < 8; i++) a2[i] = ah;
                    acc8 += hv[u] * a2;
                }
            } else {
                half4 hv[8];
#pragma unroll
                for (int u = 0; u < 8; u++)
                    hv[u] = *(const half4*)(h + (size_t)ss[u] * HC + ch);
#pragma unroll
                for (int u = 0; u < 8; u++) {
                    _Float16 ah = (_Float16)av[u];
                    half4 a2;
#pragma unroll
                    for (int i = 0; i < 4; i++) a2[i] = ah;
                    acc4 += hv[u] * a2;
                }
            }
        }
        for (; t < deg; t++) {
            int s2 = lds_src[wv][t];
            _Float16 ah = (_Float16)lds_alpha[wv][t * H + hh];
            if constexpr (V == 8) {
                half8 hv = *(const half8*)(h + (size_t)s2 * HC + ch);
                half8 a2;
#pragma unroll
                for (int i = 0; i < 8; i++) a2[i] = ah;
                acc8 += hv * a2;
            } else {
                half4 hv = *(const half4*)(h + (size_t)s2 * HC + ch);
                half4 a2;
#pragma unroll
                for (int i = 0; i < 4; i++) a2[i] = ah;
                acc4 += hv * a2;
            }
        }
    } else {
        // general path (deg > 64): strided stats with recompute, chunked agg
        float m[H], sum[H];
#pragma unroll
        for (int j = 0; j < H; j++) m[j] = -3.402823466e38f;
        for (int e = beg + lane; e < end; e += 64) {
            int s = csrc[e];
#pragma unroll
            for (int g = 0; g < H4; g++) {
                float4 as = *(const float4*)(al_s + (size_t)s * H + g * 4);
                m[g * 4 + 0] = fmaxf(m[g * 4 + 0], lrelu(as.x + ad[g * 4 + 0]));
                m[g * 4 + 1] = fmaxf(m[g * 4 + 1], lrelu(as.y + ad[g * 4 + 1]));
                m[g * 4 + 2] = fmaxf(m[g * 4 + 2], lrelu(as.z + ad[g * 4 + 2]));
                m[g * 4 + 3] = fmaxf(m[g * 4 + 3], lrelu(as.w + ad[g * 4 + 3]));
            }
        }
#pragma unroll
        for (int off = 32; off >= 1; off >>= 1)
#pragma unroll
            for (int j = 0; j < H; j++) m[j] = fmaxf(m[j], __shfl_xor(m[j], off));
#pragma unroll
        for (int j = 0; j < H; j++) sum[j] = 0.f;
        for (int e = beg + lane; e < end; e += 64) {
            int s = csrc[e];
#pragma unroll
            for (int g = 0; g < H4; g++) {
                float4 as = *(const float4*)(al_s + (size_t)s * H + g * 4);
                sum[g * 4 + 0] += __expf(lrelu(as.x + ad[g * 4 + 0]) - m[g * 4 + 0]);
                sum[g * 4 + 1] += __expf(lrelu(as.y + ad[g * 4 + 1]) - m[g * 4 + 1]);
                sum[g * 4 + 2] += __expf(lrelu(as.z + ad[g * 4 + 2]) - m[g * 4 + 2]);
                sum[g * 4 + 3] += __expf(lrelu(as.w + ad[g * 4 + 3]) - m[g * 4 + 3]);
            }
        }
#pragma unroll
        for (int off = 32; off >= 1; off >>= 1)
#pragma unroll
            for (int j = 0; j < H; j++) sum[j] += __shfl_xor(sum[j], off);
        float r[H];
#pragma unroll
        for (int j = 0; j < H; j++) r[j] = 1.0f / (sum[j] + 1e-16f);
        for (int base = beg; base < end; base += 64) {
            int cn = end - base < 64 ? end - base : 64;
            if (lane < cn) {
                int s = csrc[base + lane];
                lds_src[wv][lane] = s;
#pragma unroll
                for (int g = 0; g < H4; g++) {
                    float4 as = *(const float4*)(al_s + (size_t)s * H + g * 4);
                    float4 o;
                    o.x = __expf(lrelu(as.x + ad[g * 4 + 0]) - m[g * 4 + 0]) * r[g * 4 + 0];
                    o.y = __expf(lrelu(as.y + ad[g * 4 + 1]) - m[g * 4 + 1]) * r[g * 4 + 1];
                    o.z = __expf(lrelu(as.z + ad[g * 4 + 2]) - m[g * 4 + 2]) * r[g * 4 + 2];
                    o.w = __expf(lrelu(as.w + ad[g * 4 + 3]) - m[g * 4 + 3]) * r[g * 4 + 3];
                    *(float4*)&lds_alpha[wv][lane * H + g * 4] = o;
                }
            }
            for (int t = 0; t < cn; t++) {
                int s2 = lds_src[wv][t];
                _Float16 ah = (_Float16)lds_alpha[wv][t * H + hh];
                if constexpr (V == 8) {
                    half8 hv = *(const half8*)(h + (size_t)s2 * HC + ch);
                    half8 a2;
#pragma unroll
                    for (int i = 0; i < 8; i++) a2[i] = ah;
                    acc8 += hv * a2;
                } else {
                    half4 hv = *(const half4*)(h + (size_t)s2 * HC + ch);
                    half4 a2;
#pragma unroll
                    for (int i = 0; i < 4; i++) a2[i] = ah;
                    acc4 += hv * a2;
                }
            }
        }
    }

    float accf[V];
#pragma unroll
    for (int j = 0; j < V; j++)
        accf[j] = (V == 8) ? (float)acc8[j] : (float)acc4[j];

    if constexpr (MODE == 0) {
        unsigned short* out = (unsigned short*)out1v;
        unsigned short o[V];
#pragma unroll
        for (int j = 0; j < V; j++)
            o[j] = f2h(fmaxf(accf[j] + bias1[ch + j], 0.f));
        if constexpr (V == 8) {
            short8 ov;
#pragma unroll
            for (int j = 0; j < 8; j++) ov[j] = (short)o[j];
            *(short8*)(out + (size_t)n * HC + ch) = ov;
        } else {
            *(ushort4*)(out + (size_t)n * HC + ch) = make_ushort4(o[0], o[1], o[2], o[3]);
        }
    } else {
        // MODE 1: HC=256, V=4, 8 heads x 32ch -> mean over heads 0-3 / 4-7
        *(float4*)&shred[wv][ch] = make_float4(accf[0], accf[1], accf[2], accf[3]);
        if (lane < 32) {
            float v1 = (shred[wv][lane] + shred[wv][lane + 32] + shred[wv][lane + 64]
                        + shred[wv][lane + 96]) * 0.25f + bias1[lane];
            float v2 = (shred[wv][lane + 128] + shred[wv][lane + 160]
                        + shred[wv][lane + 192] + shred[wv][lane + 224]) * 0.25f
                       + bias2[lane];
            ((float*)out1v)[(size_t)n * 32 + lane] = v1;
            ((float*)out2v)[(size_t)n * 32 + lane] = v2;
        }
    }
}

// ---------------- orchestration ----------------

extern "C" void kernel_launch(void* const* d_in, const int* in_sizes, int n_in,
                              void* d_out, int out_size, void* d_ws, size_t ws_size,
                              hipStream_t stream) {
    (void)n_in; (void)out_size; (void)ws_size;
    const float* x   = (const float*)d_in[0];
    const int*   ei  = (const int*)d_in[1];
    const float* W1  = (const float*)d_in[2];
    const float* as1 = (const float*)d_in[3];
    const float* ad1 = (const float*)d_in[4];
    const float* b1  = (const float*)d_in[5];
    const float* W2  = (const float*)d_in[6];
    const float* as2 = (const float*)d_in[7];
    const float* ad2 = (const float*)d_in[8];
    const float* b2  = (const float*)d_in[9];
    const float* Wm  = (const float*)d_in[10];
    const float* a_sm = (const float*)d_in[11];
    const float* a_dm = (const float*)d_in[12];
    const float* bm  = (const float*)d_in[13];
    const float* Wl  = (const float*)d_in[14];
    const float* a_sl = (const float*)d_in[15];
    const float* a_dl = (const float*)d_in[16];
    const float* bl  = (const float*)d_in[17];
    float* outp = (float*)d_out;

    const int N  = in_sizes[0] / 256;   // 30000
    const int E  = in_sizes[1] / 2;     // 480000
    const int ET = E + N;               // with self loops
    const int gM128 = (N + 127) / 128;  // 235
    const int Mp = gM128 * 128;         // 30080 (padded rows; >= 469*64)
    const int gM64 = (N + 63) / 64;     // 469

    auto align_up = [](size_t v) { return (v + 255) & ~(size_t)255; };
    char* w = (char*)d_ws;
    int* row_ptr = (int*)w;  w += align_up((size_t)(N + 1) * 4);
    int* cnt     = (int*)w;  w += align_up((size_t)N * 4);
    int* csrc    = (int*)w;  w += align_up((size_t)ET * 4);
    float* al_s  = (float*)w; w += align_up((size_t)N * 8 * 4);
    float* al_d  = (float*)w; w += align_up((size_t)N * 8 * 4);
    unsigned short* xb   = (unsigned short*)w; w += align_up((size_t)Mp * 256 * 2);
    unsigned short* W1t  = (unsigned short*)w; w += align_up((size_t)256 * 256 * 2);
    unsigned short* W2t  = (unsigned short*)w; w += align_up((size_t)512 * 256 * 2);
    unsigned short* WmlT = (unsigned short*)w; w += align_up((size_t)256 * 512 * 2);
    unsigned short* bufH = (unsigned short*)w; w += align_up((size_t)Mp * 512 * 2);
    unsigned short* bufO = (unsigned short*)w; w += align_up((size_t)Mp * 512 * 2);

    // ---- CSR build ----
    int gzE = (ET + 255) / 256;
    hipMemsetAsync(cnt, 0, (size_t)N * 4, stream);
    count_edges_kernel<<<gzE, 256, 0, stream>>>(ei, E, N, cnt);
    scan_kernel<<<1, 1024, 0, stream>>>(cnt, row_ptr, N);   // re-zeroes cnt
    scatter_edges_kernel<<<gzE, 256, 0, stream>>>(ei, E, N, row_ptr, cnt, csrc);

    // ---- dtype prep ----
    f32_to_f16_pad4_kernel<<<((Mp * 256 / 4) + 255) / 256, 256, 0, stream>>>(
        x, xb, N, 256, Mp);
    transpose_all_kernel<<<(393216 + 255) / 256, 256, 0, stream>>>(
        W1, W2, Wm, Wl, W1t, W2t, WmlT);

    int gF = (N + 3) / 4;

    // ---- Layer 1: GAT(256 -> 4x64, concat) + ReLU ----
    gemm_f16_kernel<<<dim3(2, gM64), 256, 0, stream>>>(
        xb, W1t, bufH, N, 256, 256, al_s, al_d, as1, ad1, as1, ad1, 256, 64, 4);
    gat_fused_kernel<1, 4, 0><<<gF, 256, 0, stream>>>(
        row_ptr, csrc, al_s, al_d, bufH, b1, nullptr, bufO, nullptr, 256, 64, N);

    // ---- Layer 2: GAT(256 -> 4x128, concat) + ReLU ----
    gemm_f16_kernel<<<dim3(4, gM64), 256, 0, stream>>>(
        bufO, W2t, bufH, N, 256, 512, al_s, al_d, as2, ad2, as2, ad2, 512, 128, 4);
    gat_fused_kernel<1, 8, 0><<<gF, 256, 0, stream>>>(
        row_ptr, csrc, al_s, al_d, bufH, b2, nullptr, bufO, nullptr, 512, 128, N);

    // ---- Layers 3+4 batched: GAT(512 -> 8x32, mean per 4-head group) ----
    gemm_f16_kernel<<<dim3(2, gM64), 256, 0, stream>>>(
        bufO, WmlT, bufH, N, 512, 256, al_s, al_d, a_sm, a_dm, a_sl, a_dl, 128, 32, 8);
    gat_fused_kernel<2, 4, 1><<<gF, 256, 0, stream>>>(
        row_ptr, csrc, al_s, al_d, bufH, bm, bl, outp, outp + (size_t)N * 32, 256, 32, N);
}